// Round 16
// baseline (305.383 us; speedup 1.0000x reference)
//
#include <hip/hip_runtime.h>

// PostNormBoth: T=256-step recurrence, B=512 chains, H=256.
// R17 = R10's single-barrier P/Q pipeline (numerics verified, absmax
// 0.0127) ported onto the lean R16 body (249.5us):
//   v(t+1) = vP + C(t+1)*hn(t);  y = W.vP + [rstd*C]*(W.vQ) - [mu*rstd*C]*yG
//   -> stats(t-1) consumed as SCALARS in parallel with iter-t's MFMA;
//   ONE barrier per step.
// Lean pieces kept: variance-transpose reduce (1 ladder for both stats),
// C2-baked W/bias (bias via per-lane C-init on P-columns only), per-wave
// stats SLOTS (no atomics; overwrite semantics -> 2-buffer ping-pong is
// race-free with one barrier), coef table C(tau) precomputed in s_wt[..][5]
// (kills R10's wdot/Cn chain), weight rows (t+1)/(t-1) read fresh per iter
// (kills 10 rotation movs). Deferred window: hn(t-1) applied at iter t
// with w(t-1); retire slot t-3; 6-reg window (R10 verbatim).

#define TT 256

typedef __bf16 bf16x8 __attribute__((ext_vector_type(8)));
typedef float  f32x4  __attribute__((ext_vector_type(4)));
typedef float  f32x2  __attribute__((ext_vector_type(2)));

#define C2 2.8853900817779268f   // 2*log2(e)

__device__ __forceinline__ float tanh_pre(float u) {   // tanh, arg pre-scaled by C2
    float e = exp2f(u);
    return 1.f - __fdividef(2.f, e + 1.f);
}

template<int CTRL, int RM>
__device__ __forceinline__ float dpp_add(float v) {
    int t = __builtin_amdgcn_update_dpp(0, __float_as_int(v), CTRL, RM, 0xf, true);
    return v + __int_as_float(t);
}
// pure lane^2 permute (quad_perm [2,3,0,1])
__device__ __forceinline__ float dpp_xor2_mov(float v) {
    int t = __builtin_amdgcn_update_dpp(0, __float_as_int(v), 0x4E, 0xf, 0xf, true);
    return __int_as_float(t);
}
__device__ __forceinline__ float swap32_add(float v) {
    float a = v, b = v;
    asm("v_permlane32_swap_b32 %0, %1" : "+v"(a), "+v"(b));
    return a + b;
}
__device__ __forceinline__ float swap16_add(float v) {
    float a = v, b = v;
    asm("v_permlane16_swap_b32 %0, %1" : "+v"(a), "+v"(b));
    return a + b;
}

// ---- dynamic LDS layout (bytes) ----
// s_mem [2][64][256] f32 :      0  (131072)
// s_x   [2][256]     f32 : 131072  (2048)
// s_v   [2][4][272]  bf16: 133120  (4352)   rows: 0,1 = P(row0,1); 2,3 = Q
// s_red [2][4][8]    f32 : 137472  (256)    [buf][class(bit0=row,bit1=var)][wave]
// s_wt  [64][8]      f32 : 137728  (2048)   [w0..w4, C(tau), -, -]
// s_oacc[20]         f32 : 139776  (80)
#define SMEM_BYTES 139856

__global__ __launch_bounds__(512, 2)
void postnorm_kernel(const float* __restrict__ x,
                     const float* __restrict__ W_embed,
                     const float* __restrict__ b_embed,
                     const float* __restrict__ W_update,
                     const float* __restrict__ b_update,
                     const float* __restrict__ gamma,
                     const float* __restrict__ beta,
                     const float* __restrict__ W_out,
                     const float* __restrict__ b_out,
                     const float* __restrict__ ctx_s,
                     float* __restrict__ out)
{
    extern __shared__ __align__(16) char smem[];
    float*  s_mem  = (float*)(smem);
    float*  s_x    = (float*)(smem + 131072);
    __bf16* s_v    = (__bf16*)(smem + 133120);
    float*  s_red  = (float*)(smem + 137472);
    float*  s_wt   = (float*)(smem + 137728);
    float*  s_oacc = (float*)(smem + 139776);

    const int tid  = threadIdx.x;
    const int wave = tid >> 6;       // wave w owns W rows [32w,32w+32)
    const int lane = tid & 63;
    const int bn   = lane & 15;      // MFMA col: bit0=row, bit1=pq, bits2-3=rep
    const int quad = lane >> 4;
    const int r0   = blockIdx.x * 2;

    const int row  = bn & 1;
    const int pq   = (bn >> 1) & 1;  // 0 = P-column, 1 = Q-column
    const int rep  = bn >> 2;
    const int mt   = rep >> 1;
    const int rsel = (rep & 1) * 2 + pq;
    const int i_own = wave * 32 + mt * 16 + quad * 4 + rsel;  // bijective w/ row

    // ---- init ----
    {   f32x4 z = {0.f, 0.f, 0.f, 0.f};
        f32x4* p = (f32x4*)s_mem;
        #pragma unroll
        for (int k = 0; k < 16; ++k) p[tid + k * 512] = z;
    }
    s_x[tid] = x[(r0 + (tid >> 8)) * TT + (tid & 255)];
    if (tid < 64) s_red[tid] = 0.f;          // zero both stat buffers
    if (tid < 20) s_oacc[tid] = 0.f;

    const float csv = 1.f / (1.f + expf(-ctx_s[0]));

    // weight table: row tau = [w(tau)[0..4], C(tau)] where
    // C(tau) = 1 + csv * sum_k w(tau)[k]*w(tau-1)[k+1]
    if (tid < 64) {
        float wv[5], wp[5]; float sa = 0.f, sb = 0.f;
        const int pm = (tid + 63) & 63;      // tau-1
        #pragma unroll
        for (int k = 0; k < 5; ++k) {
            int ia = (tid + k - 2) & 63;
            float da = (float)ia - (float)tid;
            wv[k] = expf(-(da * da) * 0.125f);  sa += wv[k];   // TAU=8
            int ib = (pm + k - 2) & 63;
            float db = (float)ib - (float)pm;
            wp[k] = expf(-(db * db) * 0.125f);  sb += wp[k];
        }
        float ra = 1.f / sa, rb2 = 1.f / sb;
        #pragma unroll
        for (int k = 0; k < 5; ++k) { wv[k] *= ra; wp[k] *= rb2; }
        #pragma unroll
        for (int k = 0; k < 5; ++k) s_wt[tid * 8 + k] = wv[k];
        float cd = (wv[0] * wp[1] + wv[1] * wp[2]) + (wv[2] * wp[3] + wv[3] * wp[4]);
        s_wt[tid * 8 + 5] = fmaf(csv, cd, 1.f);
    }

    // per-owned-i params (embed side pre-scaled for exp2 tanh)
    const float we2 = W_embed[i_own] * C2;
    const float be2 = b_embed[i_own] * C2;
    const float gm  = gamma[i_own];
    const float btt = beta[i_own];

    // per-lane MFMA C-init: b_update*C2 on P-columns only (pq==0)
    f32x4 bu4a = *(const f32x4*)(b_update + wave * 32 + quad * 4);
    f32x4 bu4b = *(const f32x4*)(b_update + wave * 32 + 16 + quad * 4);
    const f32x4 z4 = {0.f, 0.f, 0.f, 0.f};
    f32x4 cinA, cinB;
    #pragma unroll
    for (int j = 0; j < 4; ++j) {
        cinA[j] = pq ? 0.f : bu4a[j] * C2;
        cinB[j] = pq ? 0.f : bu4b[j] * C2;
    }

    // ---- W_update -> bf16 MFMA A-fragments, PRE-SCALED by C2 ----
    bf16x8 wfa[2][8];
    #pragma unroll
    for (int m = 0; m < 2; ++m) {
        #pragma unroll
        for (int kt = 0; kt < 8; ++kt) {
            const float* wpp = W_update + (wave * 32 + m * 16 + bn) * 256
                                        + kt * 32 + quad * 8;
            f32x4 a = *(const f32x4*)wpp;
            f32x4 bb = *(const f32x4*)(wpp + 4);
            bf16x8 f;
            f[0] = (__bf16)(a[0] * C2);  f[1] = (__bf16)(a[1] * C2);
            f[2] = (__bf16)(a[2] * C2);  f[3] = (__bf16)(a[3] * C2);
            f[4] = (__bf16)(bb[0] * C2); f[5] = (__bf16)(bb[1] * C2);
            f[6] = (__bf16)(bb[2] * C2); f[7] = (__bf16)(bb[3] * C2);
            wfa[m][kt] = f;
        }
    }

    // ---- prologue A: all 4 v-rows = gm -> yG2 = (C2*W).gm at my i ----
    s_v[row * 272 + i_own]       = (__bf16)gm;
    s_v[(row + 2) * 272 + i_own] = (__bf16)gm;
    __syncthreads();
    float yG2;
    {
        const __bf16* vs0 = s_v + (bn & 3) * 272 + quad * 8;
        f32x4 a0a = z4, a0b = z4, a1a = z4, a1b = z4;
        #pragma unroll
        for (int kt = 0; kt < 4; ++kt) {
            bf16x8 b0 = *(const bf16x8*)(vs0 + kt * 32);
            bf16x8 b1 = *(const bf16x8*)(vs0 + (kt + 4) * 32);
            a0a = __builtin_amdgcn_mfma_f32_16x16x32_bf16(wfa[0][kt],     b0, a0a, 0, 0, 0);
            a1a = __builtin_amdgcn_mfma_f32_16x16x32_bf16(wfa[1][kt],     b0, a1a, 0, 0, 0);
            a0b = __builtin_amdgcn_mfma_f32_16x16x32_bf16(wfa[0][kt + 4], b1, a0b, 0, 0, 0);
            a1b = __builtin_amdgcn_mfma_f32_16x16x32_bf16(wfa[1][kt + 4], b1, a1b, 0, 0, 0);
        }
        f32x4 y0 = a0a + a0b, y1 = a1a + a1b;
        f32x4 ym = mt ? y1 : y0;
        float pl = (rep & 1) ? ym[2] : ym[0];
        float ph = (rep & 1) ? ym[3] : ym[1];
        yG2 = pq ? ph : pl;                  // ym[rsel]
    }
    __syncthreads();   // reads done before buf0 overwritten

    // ---- prologue B: v(0) into buf0: vP = inp0, vQ = 0 ----
    {
        float inp0 = tanh_pre(fmaf(s_x[row * 256], we2, be2));
        s_v[row * 272 + i_own]       = (__bf16)inp0;
        s_v[(row + 2) * 272 + i_own] = (__bf16)0.f;
    }
    float u0 = 0.f, u1 = 0.f, u2 = 0.f, u3 = 0.f, u4 = 0.f, u5 = 0.f;
    float yt_prev = 0.f, Ccur = 1.f;
    float nf = 0.f;                          // admit slot 3 (zero-init)
    float xn = s_x[row * 256 + 1];
    float* mcol = s_mem + (row << 14) + i_own;
    __syncthreads();   // v(0) visible

    #pragma unroll 1
    for (int t = 0; t < TT; ++t) {
        const int rb = t & 1, wb = rb ^ 1;
        const float m0 = (t == 0) ? 0.f : 1.f;

        // --- early reads: stats(t-1) partials + weight rows (overlap MFMA) ---
        const float* rp = s_red + wb * 32;
        f32x4 p1a = *(const f32x4*)(rp + row * 8);
        f32x4 p1b = *(const f32x4*)(rp + row * 8 + 4);
        f32x4 p2a = *(const f32x4*)(rp + (2 + row) * 8);
        f32x4 p2b = *(const f32x4*)(rp + (2 + row) * 8 + 4);
        const float* wrN = s_wt + ((t + 1) & 63) * 8;   // w(t+1), C(t+1)
        f32x4 nww = *(const f32x4*)wrN;
        f32x2 nwc = *(const f32x2*)(wrN + 4);
        const float* wrM = s_wt + ((t + 63) & 63) * 8;  // w(t-1)
        f32x4 mww = *(const f32x4*)wrM;
        float mw4 = wrM[4];
        float inp = tanh_pre(fmaf(xn, we2, be2));

        // --- MFMA on buf rb (4 real B-cols: row x {P,Q}) ---
        const __bf16* vsrc = s_v + (rb * 4 + (bn & 3)) * 272 + quad * 8;
        f32x4 a0a = cinA, a1a = cinB, a0b = z4, a1b = z4;
        #pragma unroll
        for (int kt = 0; kt < 4; ++kt) {
            bf16x8 b0 = *(const bf16x8*)(vsrc + kt * 32);
            bf16x8 b1 = *(const bf16x8*)(vsrc + (kt + 4) * 32);
            a0a = __builtin_amdgcn_mfma_f32_16x16x32_bf16(wfa[0][kt],     b0, a0a, 0, 0, 0);
            a1a = __builtin_amdgcn_mfma_f32_16x16x32_bf16(wfa[1][kt],     b0, a1a, 0, 0, 0);
            a0b = __builtin_amdgcn_mfma_f32_16x16x32_bf16(wfa[0][kt + 4], b1, a0b, 0, 0, 0);
            a1b = __builtin_amdgcn_mfma_f32_16x16x32_bf16(wfa[1][kt + 4], b1, a1b, 0, 0, 0);
        }

        // --- stats(t-1) finalize (overlapped with MFMA) ---
        float S1 = ((p1a[0] + p1a[1]) + (p1a[2] + p1a[3]))
                 + ((p1b[0] + p1b[1]) + (p1b[2] + p1b[3]));
        float S2 = ((p2a[0] + p2a[1]) + (p2a[2] + p2a[3]))
                 + ((p2b[0] + p2b[1]) + (p2b[2] + p2b[3]));
        float mu   = S1 * (1.f / 256.f);
        float var  = S2 * (1.f / 256.f) - mu * mu;
        float rstd = rsqrtf(var + 1e-5f);
        float aC = rstd * Ccur * m0;         // rstd(t-1)*C(t)
        float bC = -mu * aC;

        // --- combine: u = uP(+bias) + aC*uQ + bC*yG2 ---
        f32x4 y0 = a0a + a0b, y1 = a1a + a1b;
        f32x4 ym = mt ? y1 : y0;
        float pl = (rep & 1) ? ym[2] : ym[0];
        float ph = (rep & 1) ? ym[3] : ym[1];
        float own  = pq ? ph : pl;           // ym[rsel]  : my column @ my i
        float give = pq ? pl : ph;           // ym[rsel^1]: partner's i
        float recv = dpp_xor2_mov(give);     // other vector @ my i
        float yP = pq ? recv : own;
        float yQ = pq ? own  : recv;
        float u  = fmaf(bC, yG2, fmaf(aC, yQ, yP));
        float yt = tanh_pre(u);

        // --- lean reduce (variance-channel on bit1), per-wave slot write ---
        float e  = dpp_xor2_mov(yt);
        float v0 = yt + e;
        float v1 = fmaf(e, e, yt * yt);
        float s  = ((lane >> 1) & 1) ? v1 : v0;
        s = dpp_add<0x124, 0xf>(s);          // ror:4
        s = dpp_add<0x128, 0xf>(s);          // ror:8
        s = swap16_add(s);                   // bit4
        s = swap32_add(s);                   // bit5
        if (lane < 4) s_red[rb * 32 + lane * 8 + wave] = s;

        // --- deferred window: hn(t-1) with w(t-1); retire slot t-3 ---
        float hn = m0 * fmaf(yt_prev - mu, rstd * gm, btt);
        u0 = fmaf(mww[0], hn, u0); u1 = fmaf(mww[1], hn, u1);
        u2 = fmaf(mww[2], hn, u2); u3 = fmaf(mww[3], hn, u3);
        u4 = fmaf(mw4,    hn, u4);
        mcol[((t + 61) & 63) << 8] = u0;     // slot (t-3)&63 (complete)
        u0 = u1; u1 = u2; u2 = u3; u3 = u4; u4 = u5; u5 = nf;
        // u1..u5 = slots t-1..t+3 (contributions through hn(t-1))

        // --- vP/vQ(t+1) ---
        float ctxB = ((nww[0] * u1 + nww[1] * u2) + (nww[2] * u3 + nww[3] * u4))
                   + nwc[0] * u5;
        float vP = fmaf(nwc[1], btt, fmaf(csv, ctxB, inp));
        float vQ = gm * yt;
        __bf16* svw = s_v + wb * 1088;
        svw[row * 272 + i_own]       = (__bf16)vP;
        svw[(row + 2) * 272 + i_own] = (__bf16)vQ;

        // --- carries + prefetch ---
        Ccur = nwc[1];  yt_prev = yt;
        nf = mcol[((t + 4) & 63) << 8];      // same-thread column: no hazard
        xn = s_x[row * 256 + ((t + 2) & 255)];
        __syncthreads();   // ONE barrier: stats + v(t+1) visible
    }

    // --- epilogue: h(255) from stats(255) (buf rb(255)=1) ---
    {
        const float* rp = s_red + 1 * 32;
        f32x4 p1a = *(const f32x4*)(rp + row * 8);
        f32x4 p1b = *(const f32x4*)(rp + row * 8 + 4);
        f32x4 p2a = *(const f32x4*)(rp + (2 + row) * 8);
        f32x4 p2b = *(const f32x4*)(rp + (2 + row) * 8 + 4);
        float S1 = ((p1a[0] + p1a[1]) + (p1a[2] + p1a[3]))
                 + ((p1b[0] + p1b[1]) + (p1b[2] + p1b[3]));
        float S2 = ((p2a[0] + p2a[1]) + (p2a[2] + p2a[3]))
                 + ((p2b[0] + p2b[1]) + (p2b[2] + p2b[3]));
        float mu   = S1 * (1.f / 256.f);
        float var  = S2 * (1.f / 256.f) - mu * mu;
        float rstd = rsqrtf(var + 1e-5f);
        float hfin = fmaf(yt_prev - mu, rstd * gm, btt);
        s_x[row * 256 + i_own] = hfin;       // stage to tid-order
    }
    __syncthreads();
    {
        const int n = tid >> 8, i = tid & 255;
        float h = s_x[tid];
        #pragma unroll
        for (int o = 0; o < 10; ++o) {
            float p = h * W_out[o * 256 + i];
            #pragma unroll
            for (int m = 32; m >= 1; m >>= 1) p += __shfl_xor(p, m, 64);
            if (lane == 0) atomicAdd(&s_oacc[n * 10 + o], p);
        }
    }
    __syncthreads();
    if (tid < 20) {
        int nn = tid / 10, o = tid % 10;
        out[(r0 + nn) * 10 + o] = s_oacc[tid] + b_out[o];
    }
}

extern "C" void kernel_launch(void* const* d_in, const int* in_sizes, int n_in,
                              void* d_out, int out_size, void* d_ws, size_t ws_size,
                              hipStream_t stream) {
    const float* x    = (const float*)d_in[0];
    const float* W_e  = (const float*)d_in[1];
    const float* b_e  = (const float*)d_in[2];
    const float* W_u  = (const float*)d_in[3];
    const float* b_u  = (const float*)d_in[4];
    const float* gmm  = (const float*)d_in[5];
    const float* bta  = (const float*)d_in[6];
    const float* W_o  = (const float*)d_in[7];
    const float* b_o  = (const float*)d_in[8];
    const float* cst  = (const float*)d_in[9];
    float* out = (float*)d_out;

    (void)hipFuncSetAttribute(reinterpret_cast<const void*>(postnorm_kernel),
                              hipFuncAttributeMaxDynamicSharedMemorySize,
                              SMEM_BYTES);

    postnorm_kernel<<<dim3(256), dim3(512), SMEM_BYTES, stream>>>(
        x, W_e, b_e, W_u, b_u, gmm, bta, W_o, b_o, cst, out);
}

// Round 20
// 287.476 us; speedup vs baseline: 1.0623x; 1.0623x over previous
//
#include <hip/hip_runtime.h>

// PostNormBoth: T=256-step recurrence, B=512 chains, H=256.
// R21 = R16 BYTE-EXACT RESTORE (session-best verified: 249.5us, passed).
// R17-R20 post-mortems: single-barrier P/Q (R17) passed but slower (277);
// R18/R19/R20 all failed absmax ~1 with mutually-inconsistent bisection
// results -> the permlane-swap inline asm is correctness-fragile under
// register-pressure perturbation (and the "+&v" rewrite is itself unsafe),
// and further micro-opts carry ~50% empirical fail risk for <=2% gain.
// This kernel: R12 chassis + variance-transpose reduce + C2-baked W/bias.
//  - 256 blocks x 512 thr, 2 rows/block, 2 barriers/step, 1 wg/CU.
//  - MFMA matvec (16x16x32 bf16, W resident in VGPRs, bias in C-init).
//  - LN stats: 1-ladder variance-channel-transposed reduce (bit1 = s1/s2
//    axis), 4 atomicAdd slots, t&1 ping-pong; finalize = one b64 read.
//  - ctx decomposition: v = base + coef*hn with base/coef pre-barrier.
//  - sliding 5-slot register window + LDS slot memory, per-step
//    retire/admit prefetched across the loop-end barrier.
// Remaining floor: serial chain MFMA->tanh->reduce->stats->LN->v at
// 1 wg/CU (~2340 cyc/step). Occupancy, barrier-count, DS-count,
// DS-latency, chain-VALU: all exhausted or falsified as levers (R1-R20).

#define TT 256

typedef __bf16 bf16x8 __attribute__((ext_vector_type(8)));
typedef float  f32x4  __attribute__((ext_vector_type(4)));
typedef float  f32x2  __attribute__((ext_vector_type(2)));

#define C2 2.8853900817779268f   // 2*log2(e)

__device__ __forceinline__ float tanh_pre(float u) {   // tanh with pre-scaled arg
    float e = exp2f(u);
    return 1.f - __fdividef(2.f, e + 1.f);
}

template<int CTRL, int RM>
__device__ __forceinline__ float dpp_add(float v) {
    int t = __builtin_amdgcn_update_dpp(0, __float_as_int(v), CTRL, RM, 0xf, true);
    return v + __int_as_float(t);
}
// pure lane^2 permute (quad_perm [2,3,0,1])
__device__ __forceinline__ float dpp_xor2_mov(float v) {
    int t = __builtin_amdgcn_update_dpp(0, __float_as_int(v), 0x4E, 0xf, 0xf, true);
    return __int_as_float(t);
}
__device__ __forceinline__ float swap32_add(float v) {
    float a = v, b = v;
    asm("v_permlane32_swap_b32 %0, %1" : "+v"(a), "+v"(b));
    return a + b;
}
__device__ __forceinline__ float swap16_add(float v) {
    float a = v, b = v;
    asm("v_permlane16_swap_b32 %0, %1" : "+v"(a), "+v"(b));
    return a + b;
}

// ---- dynamic LDS layout (bytes) ----
// s_mem [2][64][256] f32 :      0  (131072)
// s_x   [2][256]     f32 : 131072  (2048)
// s_v   [2][288]     bf16: 133120  (1152)
// s_acc [2][2][2]    f32 : 134272  (32)
// s_wt  [64][8]      f32 : 134304  (2048)
// s_oacc[20]         f32 : 136352  (80)
#define SMEM_BYTES 136432

__global__ __launch_bounds__(512, 2)
void postnorm_kernel(const float* __restrict__ x,
                     const float* __restrict__ W_embed,
                     const float* __restrict__ b_embed,
                     const float* __restrict__ W_update,
                     const float* __restrict__ b_update,
                     const float* __restrict__ gamma,
                     const float* __restrict__ beta,
                     const float* __restrict__ W_out,
                     const float* __restrict__ b_out,
                     const float* __restrict__ ctx_s,
                     float* __restrict__ out)
{
    extern __shared__ __align__(16) char smem[];
    float*  s_mem  = (float*)(smem);
    float*  s_x    = (float*)(smem + 131072);
    __bf16* s_v    = (__bf16*)(smem + 133120);
    float*  s_acc  = (float*)(smem + 134272);
    float*  s_wt   = (float*)(smem + 134304);
    float*  s_oacc = (float*)(smem + 136352);

    const int tid  = threadIdx.x;
    const int wave = tid >> 6;       // wave w owns W rows [32w,32w+32)
    const int lane = tid & 63;
    const int bn   = lane & 15;      // MFMA col
    const int quad = lane >> 4;
    const int r0   = blockIdx.x * 2;

    // ownership: this lane's accumulators hold y[i_own] for row `row`
    const int b     = bn >> 1;
    const int row   = bn & 1;
    const int i_own = wave * 32 + (b >> 2) * 16 + quad * 4 + (b & 3);

    // ---- init ----
    {   f32x4 z = {0.f, 0.f, 0.f, 0.f};
        f32x4* p = (f32x4*)s_mem;
        #pragma unroll
        for (int k = 0; k < 16; ++k) p[tid + k * 512] = z;
    }
    s_x[tid] = x[(r0 + (tid >> 8)) * TT + (tid & 255)];
    if (tid < 8)  s_acc[tid] = 0.f;
    if (tid < 20) s_oacc[tid] = 0.f;

    // weight table: pointer is t&63; row padded to 8 floats
    if (tid < 64) {
        float wv[5]; float ssum = 0.f;
        #pragma unroll
        for (int k = 0; k < 5; ++k) {
            int idx = (tid + k - 2) & 63;            // wrapped index
            float d = (float)idx - (float)tid;       // delta AFTER wrap
            wv[k] = expf(-(d * d) * 0.125f);         // TAU=8
            ssum += wv[k];
        }
        #pragma unroll
        for (int k = 0; k < 5; ++k) s_wt[tid * 8 + k] = wv[k] / ssum;
    }

    const float csv = 1.f / (1.f + expf(-ctx_s[0]));

    // per-owned-i params (embed side pre-scaled for exp2 tanh)
    const float we2 = W_embed[i_own] * C2;
    const float be2 = b_embed[i_own] * C2;
    const float gm  = gamma[i_own];
    const float btt = beta[i_own];

    // MFMA C-initializers: b_update*C2 for this lane's (quad, r) rows,
    // tile mt=0 (a0a chain) and mt=1 (a1a chain); bn-independent.
    f32x4 bu4a = *(const f32x4*)(b_update + wave * 32 + quad * 4);
    f32x4 bu4b = *(const f32x4*)(b_update + wave * 32 + 16 + quad * 4);
    #pragma unroll
    for (int j = 0; j < 4; ++j) { bu4a[j] *= C2; bu4b[j] *= C2; }

    // ---- W_update -> bf16 MFMA A-fragments, PRE-SCALED by C2 ----
    bf16x8 wfa[2][8];
    #pragma unroll
    for (int mt = 0; mt < 2; ++mt) {
        #pragma unroll
        for (int kt = 0; kt < 8; ++kt) {
            const float* wp = W_update + (wave * 32 + mt * 16 + bn) * 256
                                       + kt * 32 + quad * 8;
            f32x4 a = *(const f32x4*)wp;
            f32x4 bb = *(const f32x4*)(wp + 4);
            bf16x8 f;
            f[0] = (__bf16)(a[0] * C2);  f[1] = (__bf16)(a[1] * C2);
            f[2] = (__bf16)(a[2] * C2);  f[3] = (__bf16)(a[3] * C2);
            f[4] = (__bf16)(bb[0] * C2); f[5] = (__bf16)(bb[1] * C2);
            f[6] = (__bf16)(bb[2] * C2); f[7] = (__bf16)(bb[3] * C2);
            wfa[mt][kt] = f;
        }
    }

    __syncthreads();
    {   // v(t=0): memory==0, h==0 -> v = inp
        float inp0 = tanh_pre(fmaf(s_x[row * 256], we2, be2));
        s_v[row * 288 + i_own] = (__bf16)inp0;
    }

    // attention weights for pointer 0 + step-0 prefetches
    float wt0, wt1, wt2, wt3, wt4;
    {   f32x4 wv = *(const f32x4*)(s_wt);
        wt0 = wv[0]; wt1 = wv[1]; wt2 = wv[2]; wt3 = wv[3]; wt4 = s_wt[4];
    }
    f32x4 nw  = *(const f32x4*)(s_wt + 8);       // weights for pointer t+1
    float nw4 = s_wt[8 + 4];
    float xn  = s_x[row * 256 + 1];              // x[t+1] for own row
    float nf  = 0.f;                             // admit slot 3 (zero-init)
    __syncthreads();

    float hn = 0.f;
    // register window: slots (t-2..t+2) mod 64 of memory column (row,i_own)
    float w0 = 0.f, w1 = 0.f, w2 = 0.f, w3 = 0.f, w4 = 0.f;
    float* mcol = s_mem + (row << 14) + i_own;
    const __bf16* vsrc = s_v + row * 288 + quad * 8;

    #pragma unroll 1
    for (int t = 0; t < TT; ++t) {
        const int rb = t & 1, wb = rb ^ 1;

        // --- pre-barrier: everything not depending on stats(t) ---
        float inp  = tanh_pre(fmaf(xn, we2, be2));
        float ctxA = ((nw[0] * w1 + nw[1] * w2) + (nw[2] * w3 + nw[3] * w4))
                   + nw4 * nf;
        float wdot = (nw[0] * wt1 + nw[1] * wt2) + (nw[2] * wt3 + nw[3] * wt4);
        float base = fmaf(csv, ctxA, inp);
        float coef = fmaf(csv, wdot, 1.f);

        // --- P1: u = C2*(W.v + bu) via MFMA (bias in C-init, W pre-scaled) ---
        f32x4 a0a = bu4a, a1a = bu4b;
        f32x4 a0b = {0,0,0,0}, a1b = {0,0,0,0};
        #pragma unroll
        for (int kt = 0; kt < 4; ++kt) {
            bf16x8 bfr0 = *(const bf16x8*)(vsrc + kt * 32);
            bf16x8 bfr1 = *(const bf16x8*)(vsrc + (kt + 4) * 32);
            a0a = __builtin_amdgcn_mfma_f32_16x16x32_bf16(wfa[0][kt],     bfr0, a0a, 0, 0, 0);
            a1a = __builtin_amdgcn_mfma_f32_16x16x32_bf16(wfa[1][kt],     bfr0, a1a, 0, 0, 0);
            a0b = __builtin_amdgcn_mfma_f32_16x16x32_bf16(wfa[0][kt + 4], bfr1, a0b, 0, 0, 0);
            a1b = __builtin_amdgcn_mfma_f32_16x16x32_bf16(wfa[1][kt + 4], bfr1, a1b, 0, 0, 0);
        }

        // --- select owned u from regs: (mt,r) = (b>>2, b&3) ---
        f32x4 y0 = a0a + a0b, y1 = a1a + a1b;
        f32x4 ym = (b & 4) ? y1 : y0;
        float yA = (b & 2) ? ym[2] : ym[0];
        float yB = (b & 2) ? ym[3] : ym[1];
        float ysel = (b & 1) ? yB : yA;

        // --- P2: tanh + variance-channel-transposed reduce ---
        float yt = tanh_pre(ysel);                 // bias already inside
        float e  = dpp_xor2_mov(yt);               // partner (lane^2) yt
        float v0 = yt + e;                         // s1 pair-sum
        float v1 = fmaf(e, e, yt * yt);            // s2 pair-sum
        float s  = ((lane >> 1) & 1) ? v1 : v0;    // bit1 = variance channel
        s = dpp_add<0x124, 0xf>(s);                // ror:4  (bits 2,3 pt1)
        s = dpp_add<0x128, 0xf>(s);                // ror:8  (bits 2,3 pt2)
        s = swap16_add(s);                         // bit4
        s = swap32_add(s);                         // bit5
        // lane (bit0=row, bit1=var) in 0..3 holds its class's wave partial
        if (lane < 4)
            atomicAdd(&s_acc[rb * 4 + (lane & 1) * 2 + (lane >> 1)], s);
        __syncthreads();   // [1] partials summed (also fences vsrc reads)

        // --- P3: finalize = ONE b64 read; then hn -> v (1 fma + cvt) ---
        f32x2 S = *(const f32x2*)(s_acc + rb * 4 + row * 2);
        if (tid < 4) s_acc[wb * 4 + tid] = 0.f;   // reset other buf (dead now)
        float mu   = S[0] * (1.f / 256.f);
        float var  = S[1] * (1.f / 256.f) - mu * mu;
        float rstd = rsqrtf(var + 1e-5f);
        hn = fmaf(yt - mu, rstd * gm, btt);
        float v = fmaf(coef, hn, base);
        s_v[row * 288 + i_own] = (__bf16)v;        // critical write ASAP

        // --- off-chain: window scatter+slide (fused) + retire + prefetch ---
        float rv = fmaf(wt0, hn, w0);
        w0 = fmaf(wt1, hn, w1); w1 = fmaf(wt2, hn, w2);
        w2 = fmaf(wt3, hn, w3); w3 = fmaf(wt4, hn, w4); w4 = nf;
        mcol[((t - 2) & 63) << 8] = rv;            // retire slot t-2
        wt0 = nw[0]; wt1 = nw[1]; wt2 = nw[2]; wt3 = nw[3]; wt4 = nw4;
        nf  = mcol[((t + 4) & 63) << 8];           // same-thread col: no hazard
        {   const float* wp = s_wt + ((t + 2) & 63) * 8;
            nw  = *(const f32x4*)wp;
            nw4 = wp[4];
        }
        xn  = s_x[row * 256 + ((t + 2) & 255)];
        __syncthreads();   // [2] v visible
    }

    // --- epilogue: stage hn into s_x to restore tid-order ---
    s_x[row * 256 + i_own] = hn;
    __syncthreads();
    {
        const int n = tid >> 8, i = tid & 255;
        float h = s_x[tid];
        #pragma unroll
        for (int o = 0; o < 10; ++o) {
            float p = h * W_out[o * 256 + i];
            #pragma unroll
            for (int m = 32; m >= 1; m >>= 1) p += __shfl_xor(p, m, 64);
            if (lane == 0) atomicAdd(&s_oacc[n * 10 + o], p);
        }
    }
    __syncthreads();
    if (tid < 20) {
        int nn = tid / 10, o = tid % 10;
        out[(r0 + nn) * 10 + o] = s_oacc[tid] + b_out[o];
    }
}

extern "C" void kernel_launch(void* const* d_in, const int* in_sizes, int n_in,
                              void* d_out, int out_size, void* d_ws, size_t ws_size,
                              hipStream_t stream) {
    const float* x    = (const float*)d_in[0];
    const float* W_e  = (const float*)d_in[1];
    const float* b_e  = (const float*)d_in[2];
    const float* W_u  = (const float*)d_in[3];
    const float* b_u  = (const float*)d_in[4];
    const float* gmm  = (const float*)d_in[5];
    const float* bta  = (const float*)d_in[6];
    const float* W_o  = (const float*)d_in[7];
    const float* b_o  = (const float*)d_in[8];
    const float* cst  = (const float*)d_in[9];
    float* out = (float*)d_out;

    (void)hipFuncSetAttribute(reinterpret_cast<const void*>(postnorm_kernel),
                              hipFuncAttributeMaxDynamicSharedMemorySize,
                              SMEM_BYTES);

    postnorm_kernel<<<dim3(256), dim3(512), SMEM_BYTES, stream>>>(
        x, W_e, b_e, W_u, b_u, gmm, bta, W_o, b_o, cst, out);
}